// Round 6
// baseline (459.988 us; speedup 1.0000x reference)
//
#include <hip/hip_runtime.h>
#include <hip/hip_bf16.h>

#define DIM 128
#define WS_LD 132   // padded LDS leading dim (float4-aligned, breaks pow2 bank stride)
#define NCHUNK 256  // chunks for 2-level scan

typedef unsigned short u16;
typedef unsigned int u32;

__device__ __forceinline__ float bfbits2f(u16 u) {
    return __uint_as_float(((u32)u) << 16);
}
__device__ __forceinline__ u16 f2bf(float f) {
    __hip_bfloat16 b = __float2bfloat16(f);
    return *reinterpret_cast<u16*>(&b);
}

// ---- dtype probe: flag=1 if float tensors are f32, flag=0 if bf16 ----
__global__ void k_probe(const u16* __restrict__ x, int* __restrict__ flagp) {
    if (threadIdx.x == 0 && blockIdx.x == 0) {
        int weird = 0;
        for (int i = 0; i < 256; i += 2) {
            u16 v = x[i];
            int e = (v >> 7) & 0xff;
            if ((v & 0x7fff) != 0 && (e >= 133 || e <= 100)) weird++;
        }
        *flagp = (weird > 16) ? 1 : 0;
    }
}

// ---- CSR build ----
__global__ __launch_bounds__(256) void k_count(const int* __restrict__ dst,
                                               int* __restrict__ counts, int E) {
    int e = blockIdx.x * blockDim.x + threadIdx.x;
    if (e < E) atomicAdd(&counts[dst[e]], 1);
}

__global__ __launch_bounds__(256) void k_chunksum(const int* __restrict__ counts,
                                                  int* __restrict__ chunksum,
                                                  int N, int chunk) {
    __shared__ int r[256];
    int t = threadIdx.x, b = blockIdx.x;
    int idx = b * chunk + t;
    r[t] = (t < chunk && idx < N) ? counts[idx] : 0;
    __syncthreads();
    for (int off = 128; off > 0; off >>= 1) {
        if (t < off) r[t] += r[t + off];
        __syncthreads();
    }
    if (t == 0) chunksum[b] = r[0];
}

__global__ void k_scanbase(const int* __restrict__ chunksum,
                           int* __restrict__ chunkbase,
                           int* __restrict__ rowptr, int N) {
    if (threadIdx.x == 0 && blockIdx.x == 0) {
        int run = 0;
        for (int i = 0; i < NCHUNK; ++i) { chunkbase[i] = run; run += chunksum[i]; }
        rowptr[N] = run;
    }
}

__global__ __launch_bounds__(256) void k_rowptr(const int* __restrict__ counts,
                                                const int* __restrict__ chunkbase,
                                                int* __restrict__ rowptr,
                                                float* __restrict__ dis,
                                                int N, int chunk) {
    __shared__ int sc[256];
    int t = threadIdx.x, b = blockIdx.x;
    int idx = b * chunk + t;
    int v = (t < chunk && idx < N) ? counts[idx] : 0;
    sc[t] = v;
    __syncthreads();
    for (int off = 1; off < 256; off <<= 1) {
        int add = (t >= off) ? sc[t - off] : 0;
        __syncthreads();
        sc[t] += add;
        __syncthreads();
    }
    if (t < chunk && idx < N) {
        rowptr[idx] = chunkbase[b] + sc[t] - v;  // exclusive prefix
        dis[idx] = rsqrtf((float)v + 1.0f);
    }
}

__global__ __launch_bounds__(256) void k_fill(const int* __restrict__ src,
                                              const int* __restrict__ dst,
                                              const int* __restrict__ rowptr,
                                              int* __restrict__ cursor,
                                              u16* __restrict__ sorted_src, int E) {
    int e = blockIdx.x * blockDim.x + threadIdx.x;
    if (e < E) {
        int d = dst[e];
        int pos = rowptr[d] + atomicAdd(&cursor[d], 1);
        sorted_src[pos] = (u16)src[e];
    }
}

// ---- tiled GEMM: h[n,o] = sum_i in[n,i]*W[o,i]; h stored bf16.
// in_mode: 1 = input follows flag (layer 1); 0 = input always bf16 (layer-2 act).
__global__ __launch_bounds__(256) void k_gemm(const void* __restrict__ in,
                                              const void* __restrict__ W,
                                              u16* __restrict__ h, int N,
                                              const int* __restrict__ flagp, int in_mode) {
    __shared__ float Ws[32 * WS_LD];
    __shared__ float Xs[8][DIM];
    const int tid = threadIdx.x;
    const int n0 = blockIdx.x * 8;
    const int flag = *flagp;
    const int in_f32 = in_mode ? flag : 0;

    {   // stage X rows
        int r = tid >> 5;
        int c4 = (tid & 31) * 4;
        int n = n0 + r;
        float4 xv = make_float4(0.f, 0.f, 0.f, 0.f);
        if (n < N) {
            if (in_f32) {
                xv = *(const float4*)((const float*)in + (size_t)n * DIM + c4);
            } else {
                ushort4 q = *(const ushort4*)((const u16*)in + (size_t)n * DIM + c4);
                xv = make_float4(bfbits2f(q.x), bfbits2f(q.y), bfbits2f(q.z), bfbits2f(q.w));
            }
        }
        *(float4*)(&Xs[r][c4]) = xv;
    }

    const int node = tid >> 5;
    const int c0 = (tid & 31) * 4;
    float a0 = 0.f, a1 = 0.f, a2 = 0.f, a3 = 0.f;

    for (int kc = 0; kc < 4; ++kc) {
        __syncthreads();
        if (flag) {
            const float* Wf = (const float*)W;
            for (int t = tid; t < 32 * DIM; t += 256) {
                int o = t >> 5, ii = t & 31;
                Ws[ii * WS_LD + o] = Wf[o * DIM + kc * 32 + ii];
            }
        } else {
            const u16* Wu = (const u16*)W;
            for (int t = tid; t < 32 * DIM; t += 256) {
                int o = t >> 5, ii = t & 31;
                Ws[ii * WS_LD + o] = bfbits2f(Wu[o * DIM + kc * 32 + ii]);
            }
        }
        __syncthreads();
#pragma unroll
        for (int ii = 0; ii < 32; ++ii) {
            float xv = Xs[node][kc * 32 + ii];
            float4 w = *(const float4*)(Ws + ii * WS_LD + c0);
            a0 = fmaf(xv, w.x, a0);
            a1 = fmaf(xv, w.y, a1);
            a2 = fmaf(xv, w.z, a2);
            a3 = fmaf(xv, w.w, a3);
        }
    }
    int n = n0 + node;
    if (n < N) {
        *(ushort4*)(h + (size_t)n * DIM + c0) =
            make_ushort4(f2bf(a0), f2bf(a1), f2bf(a2), f2bf(a3));
    }
}

// ---- fused CSR aggregate: one wave per dst node d, 2 cols per lane.
// OUT_BF16=true  -> store bf16 (layer-1 activations, scratch)
// OUT_BF16=false -> store f32  (final output; reference output dtype is float32)
template <bool RELU, bool OUT_BF16>
__global__ __launch_bounds__(256) void k_agg(const u16* __restrict__ h,
                                             const float* __restrict__ dis,
                                             const int* __restrict__ rowptr,
                                             const u16* __restrict__ sorted_src,
                                             const void* __restrict__ bias,
                                             void* __restrict__ out, int N,
                                             const int* __restrict__ flagp) {
    const int lane = threadIdx.x & 63;
    const int d = blockIdx.x * 4 + (threadIdx.x >> 6);
    if (d >= N) return;
    const int flag = *flagp;

    const int start = rowptr[d];
    const int end = rowptr[d + 1];
    const float dd = dis[d];

    float acc0 = 0.f, acc1 = 0.f;
    for (int j = start; j < end; ++j) {
        int s = (int)sorted_src[j];
        float ds = dis[s];
        u32 u = *(const u32*)(h + (size_t)s * DIM + lane * 2);
        acc0 = fmaf(bfbits2f((u16)(u & 0xffff)), ds, acc0);
        acc1 = fmaf(bfbits2f((u16)(u >> 16)), ds, acc1);
    }
    acc0 *= dd;
    acc1 *= dd;
    {   // self-loop
        float d2 = dd * dd;
        u32 u = *(const u32*)(h + (size_t)d * DIM + lane * 2);
        acc0 = fmaf(bfbits2f((u16)(u & 0xffff)), d2, acc0);
        acc1 = fmaf(bfbits2f((u16)(u >> 16)), d2, acc1);
    }
    int c = lane * 2;
    float b0, b1;
    if (flag) {
        b0 = ((const float*)bias)[c];
        b1 = ((const float*)bias)[c + 1];
    } else {
        b0 = bfbits2f(((const u16*)bias)[c]);
        b1 = bfbits2f(((const u16*)bias)[c + 1]);
    }
    acc0 += b0;
    acc1 += b1;
    if (RELU) {
        acc0 = acc0 > 0.f ? acc0 : 0.01f * acc0;
        acc1 = acc1 > 0.f ? acc1 : 0.01f * acc1;
    }
    if (OUT_BF16) {
        u32 packed = (u32)f2bf(acc0) | ((u32)f2bf(acc1) << 16);
        *(u32*)((u16*)out + (size_t)d * DIM + c) = packed;
    } else {
        *(float2*)((float*)out + (size_t)d * DIM + c) = make_float2(acc0, acc1);
    }
}

extern "C" void kernel_launch(void* const* d_in, const int* in_sizes, int n_in,
                              void* d_out, int out_size, void* d_ws, size_t ws_size,
                              hipStream_t stream) {
    const void* x  = d_in[0];             // f32 (probed; flag-adaptive)
    const int*  ei = (const int*)d_in[1];
    // d_in[2] = batch (unused in eval mode)
    const void* W1 = d_in[3];
    const void* b1 = d_in[4];
    const void* W2 = d_in[5];
    const void* b2 = d_in[6];

    const int N = in_sizes[0] / DIM;
    const int E = in_sizes[1] / 2;
    const int* src = ei;
    const int* dst = ei + E;
    const int chunk = (N + NCHUNK - 1) / NCHUNK;

    // ws layout (~15 MB total; 256B-aligned slices)
    char* ws = (char*)d_ws;
    size_t o = 0;
    int*   flagp    = (int*)(ws + o);   o += 256;
    float* dis      = (float*)(ws + o); o += (((size_t)N * 4 + 255) & ~(size_t)255);
    int*   counts   = (int*)(ws + o);   o += (((size_t)N * 4 + 255) & ~(size_t)255);
    int*   rowptr   = (int*)(ws + o);   o += (((size_t)(N + 1) * 4 + 255) & ~(size_t)255);
    int*   chunksum = (int*)(ws + o);   o += 1024;
    int*   chunkbase= (int*)(ws + o);   o += 1024;
    u16*   sorted   = (u16*)(ws + o);   o += (((size_t)E * 2 + 255) & ~(size_t)255);
    u16*   h        = (u16*)(ws + o);   // N*128 bf16 = 12.8 MB

    const int eblk = (E + 255) / 256;
    const int gblk = (N + 7) / 8;
    const int ablk = (N + 3) / 4;

    // dtype probe + CSR build (shared by both layers)
    k_probe<<<1, 64, 0, stream>>>((const u16*)x, flagp);
    hipMemsetAsync(counts, 0, (size_t)N * 4, stream);
    k_count<<<eblk, 256, 0, stream>>>(dst, counts, E);
    k_chunksum<<<NCHUNK, 256, 0, stream>>>(counts, chunksum, N, chunk);
    k_scanbase<<<1, 64, 0, stream>>>(chunksum, chunkbase, rowptr, N);
    k_rowptr<<<NCHUNK, 256, 0, stream>>>(counts, chunkbase, rowptr, dis, N, chunk);
    hipMemsetAsync(counts, 0, (size_t)N * 4, stream);  // reuse as fill cursor
    k_fill<<<eblk, 256, 0, stream>>>(src, dst, rowptr, counts, sorted, E);

    // layer-1 activations (bf16) live in d_out's first 12.8 MB (d_out is 25.6 MB f32);
    // consumed by gemm2 BEFORE the final f32 aggregate overwrites d_out.
    u16* act = (u16*)d_out;

    // ---- layer 1 ----
    k_gemm<<<gblk, 256, 0, stream>>>(x, W1, h, N, flagp, 1);
    k_agg<true, true><<<ablk, 256, 0, stream>>>(h, dis, rowptr, sorted, b1, act, N, flagp);

    // ---- layer 2 ----
    k_gemm<<<gblk, 256, 0, stream>>>(act, W2, h, N, flagp, 0);
    k_agg<false, false><<<ablk, 256, 0, stream>>>(h, dis, rowptr, sorted, b2, d_out, N, flagp);
}

// Round 7
// 383.088 us; speedup vs baseline: 1.2007x; 1.2007x over previous
//
#include <hip/hip_runtime.h>
#include <hip/hip_bf16.h>
#include <hip/hip_fp16.h>

#define DIM 128
#define WS_LD 132   // padded LDS leading dim (float4-aligned, breaks pow2 bank stride)
#define NCHUNK 256  // chunks for 2-level scan

typedef unsigned short u16;
typedef unsigned int u32;

__device__ __forceinline__ float bfbits2f(u16 u) {
    return __uint_as_float(((u32)u) << 16);
}
__device__ __forceinline__ u16 f2bf(float f) {
    __hip_bfloat16 b = __float2bfloat16(f);
    return *reinterpret_cast<u16*>(&b);
}
__device__ __forceinline__ float h16tof(u16 u) {
    __half hh = *reinterpret_cast<__half*>(&u);
    return __half2float(hh);
}
__device__ __forceinline__ u16 ftoh16(float f) {
    __half hh = __float2half(f);
    return *reinterpret_cast<u16*>(&hh);
}

// ---- dtype probe: flag=1 if float tensors are f32, flag=0 if bf16 ----
__global__ void k_probe(const u16* __restrict__ x, int* __restrict__ flagp) {
    if (threadIdx.x == 0 && blockIdx.x == 0) {
        int weird = 0;
        for (int i = 0; i < 256; i += 2) {
            u16 v = x[i];
            int e = (v >> 7) & 0xff;
            if ((v & 0x7fff) != 0 && (e >= 133 || e <= 100)) weird++;
        }
        *flagp = (weird > 16) ? 1 : 0;
    }
}

// ---- CSR build ----
__global__ __launch_bounds__(256) void k_count(const int* __restrict__ dst,
                                               int* __restrict__ counts, int E) {
    int e = blockIdx.x * blockDim.x + threadIdx.x;
    if (e < E) atomicAdd(&counts[dst[e]], 1);
}

__global__ __launch_bounds__(256) void k_chunksum(const int* __restrict__ counts,
                                                  int* __restrict__ chunksum,
                                                  int N, int chunk) {
    __shared__ int r[256];
    int t = threadIdx.x, b = blockIdx.x;
    int idx = b * chunk + t;
    r[t] = (t < chunk && idx < N) ? counts[idx] : 0;
    __syncthreads();
    for (int off = 128; off > 0; off >>= 1) {
        if (t < off) r[t] += r[t + off];
        __syncthreads();
    }
    if (t == 0) chunksum[b] = r[0];
}

__global__ void k_scanbase(const int* __restrict__ chunksum,
                           int* __restrict__ chunkbase,
                           int* __restrict__ rowptr, int N) {
    if (threadIdx.x == 0 && blockIdx.x == 0) {
        int run = 0;
        for (int i = 0; i < NCHUNK; ++i) { chunkbase[i] = run; run += chunksum[i]; }
        rowptr[N] = run;
    }
}

__global__ __launch_bounds__(256) void k_rowptr(const int* __restrict__ counts,
                                                const int* __restrict__ chunkbase,
                                                int* __restrict__ rowptr,
                                                float* __restrict__ dis,
                                                int N, int chunk) {
    __shared__ int sc[256];
    int t = threadIdx.x, b = blockIdx.x;
    int idx = b * chunk + t;
    int v = (t < chunk && idx < N) ? counts[idx] : 0;
    sc[t] = v;
    __syncthreads();
    for (int off = 1; off < 256; off <<= 1) {
        int add = (t >= off) ? sc[t - off] : 0;
        __syncthreads();
        sc[t] += add;
        __syncthreads();
    }
    if (t < chunk && idx < N) {
        rowptr[idx] = chunkbase[b] + sc[t] - v;  // exclusive prefix
        dis[idx] = rsqrtf((float)v + 1.0f);
    }
}

// ---- counting-sort fill with packed payload: elist[pos] = (src<<16) | f16(dis[src]) ----
__global__ __launch_bounds__(256) void k_fill(const int* __restrict__ src,
                                              const int* __restrict__ dst,
                                              const int* __restrict__ rowptr,
                                              int* __restrict__ cursor,
                                              const float* __restrict__ dis,
                                              u32* __restrict__ elist, int E) {
    int e = blockIdx.x * blockDim.x + threadIdx.x;
    if (e < E) {
        int d = dst[e];
        int s = src[e];
        int pos = rowptr[d] + atomicAdd(&cursor[d], 1);
        elist[pos] = ((u32)s << 16) | (u32)ftoh16(dis[s]);
    }
}

// ---- tiled GEMM: h[n,o] = sum_i in[n,i]*W[o,i]; h stored bf16.
// in_mode: 1 = input follows flag (layer 1); 0 = input always bf16 (layer-2 act).
__global__ __launch_bounds__(256) void k_gemm(const void* __restrict__ in,
                                              const void* __restrict__ W,
                                              u16* __restrict__ h, int N,
                                              const int* __restrict__ flagp, int in_mode) {
    __shared__ float Ws[32 * WS_LD];
    __shared__ float Xs[8][DIM];
    const int tid = threadIdx.x;
    const int n0 = blockIdx.x * 8;
    const int flag = *flagp;
    const int in_f32 = in_mode ? flag : 0;

    {   // stage X rows
        int r = tid >> 5;
        int c4 = (tid & 31) * 4;
        int n = n0 + r;
        float4 xv = make_float4(0.f, 0.f, 0.f, 0.f);
        if (n < N) {
            if (in_f32) {
                xv = *(const float4*)((const float*)in + (size_t)n * DIM + c4);
            } else {
                ushort4 q = *(const ushort4*)((const u16*)in + (size_t)n * DIM + c4);
                xv = make_float4(bfbits2f(q.x), bfbits2f(q.y), bfbits2f(q.z), bfbits2f(q.w));
            }
        }
        *(float4*)(&Xs[r][c4]) = xv;
    }

    const int node = tid >> 5;
    const int c0 = (tid & 31) * 4;
    float a0 = 0.f, a1 = 0.f, a2 = 0.f, a3 = 0.f;

    for (int kc = 0; kc < 4; ++kc) {
        __syncthreads();
        if (flag) {
            const float* Wf = (const float*)W;
            for (int t = tid; t < 32 * DIM; t += 256) {
                int o = t >> 5, ii = t & 31;
                Ws[ii * WS_LD + o] = Wf[o * DIM + kc * 32 + ii];
            }
        } else {
            const u16* Wu = (const u16*)W;
            for (int t = tid; t < 32 * DIM; t += 256) {
                int o = t >> 5, ii = t & 31;
                Ws[ii * WS_LD + o] = bfbits2f(Wu[o * DIM + kc * 32 + ii]);
            }
        }
        __syncthreads();
#pragma unroll
        for (int ii = 0; ii < 32; ++ii) {
            float xv = Xs[node][kc * 32 + ii];
            float4 w = *(const float4*)(Ws + ii * WS_LD + c0);
            a0 = fmaf(xv, w.x, a0);
            a1 = fmaf(xv, w.y, a1);
            a2 = fmaf(xv, w.z, a2);
            a3 = fmaf(xv, w.w, a3);
        }
    }
    int n = n0 + node;
    if (n < N) {
        *(ushort4*)(h + (size_t)n * DIM + c0) =
            make_ushort4(f2bf(a0), f2bf(a1), f2bf(a2), f2bf(a3));
    }
}

// ---- fused CSR aggregate: one wave per dst node d, 2 cols per lane.
// Unrolled x4 with independent accumulators; packed (src|f16 dis) edge payload.
// OUT_BF16=true -> bf16 store (layer-1 act); false -> f32 store (final output).
template <bool RELU, bool OUT_BF16>
__global__ __launch_bounds__(256) void k_agg(const u16* __restrict__ h,
                                             const float* __restrict__ dis,
                                             const int* __restrict__ rowptr,
                                             const u32* __restrict__ elist,
                                             const void* __restrict__ bias,
                                             void* __restrict__ out, int N,
                                             const int* __restrict__ flagp) {
    const int lane = threadIdx.x & 63;
    const int d = blockIdx.x * 4 + (threadIdx.x >> 6);
    if (d >= N) return;
    const int flag = *flagp;

    const int start = rowptr[d];
    const int end = rowptr[d + 1];
    const float dd = dis[d];

    float p0 = 0.f, p1 = 0.f, q0 = 0.f, q1 = 0.f;
    float r0 = 0.f, r1 = 0.f, t0 = 0.f, t1 = 0.f;

    int j = start;
    for (; j + 4 <= end; j += 4) {
        u32 e0 = elist[j];
        u32 e1 = elist[j + 1];
        u32 e2 = elist[j + 2];
        u32 e3 = elist[j + 3];
        float w0 = h16tof((u16)(e0 & 0xffff));
        float w1 = h16tof((u16)(e1 & 0xffff));
        float w2 = h16tof((u16)(e2 & 0xffff));
        float w3 = h16tof((u16)(e3 & 0xffff));
        u32 u0 = *(const u32*)(h + ((size_t)(e0 >> 16)) * DIM + lane * 2);
        u32 u1 = *(const u32*)(h + ((size_t)(e1 >> 16)) * DIM + lane * 2);
        u32 u2 = *(const u32*)(h + ((size_t)(e2 >> 16)) * DIM + lane * 2);
        u32 u3 = *(const u32*)(h + ((size_t)(e3 >> 16)) * DIM + lane * 2);
        p0 = fmaf(bfbits2f((u16)(u0 & 0xffff)), w0, p0);
        p1 = fmaf(bfbits2f((u16)(u0 >> 16)), w0, p1);
        q0 = fmaf(bfbits2f((u16)(u1 & 0xffff)), w1, q0);
        q1 = fmaf(bfbits2f((u16)(u1 >> 16)), w1, q1);
        r0 = fmaf(bfbits2f((u16)(u2 & 0xffff)), w2, r0);
        r1 = fmaf(bfbits2f((u16)(u2 >> 16)), w2, r1);
        t0 = fmaf(bfbits2f((u16)(u3 & 0xffff)), w3, t0);
        t1 = fmaf(bfbits2f((u16)(u3 >> 16)), w3, t1);
    }
    for (; j < end; ++j) {
        u32 e0 = elist[j];
        float w0 = h16tof((u16)(e0 & 0xffff));
        u32 u0 = *(const u32*)(h + ((size_t)(e0 >> 16)) * DIM + lane * 2);
        p0 = fmaf(bfbits2f((u16)(u0 & 0xffff)), w0, p0);
        p1 = fmaf(bfbits2f((u16)(u0 >> 16)), w0, p1);
    }
    float acc0 = (p0 + q0) + (r0 + t0);
    float acc1 = (p1 + q1) + (r1 + t1);
    acc0 *= dd;
    acc1 *= dd;
    {   // self-loop
        float d2 = dd * dd;
        u32 u = *(const u32*)(h + (size_t)d * DIM + lane * 2);
        acc0 = fmaf(bfbits2f((u16)(u & 0xffff)), d2, acc0);
        acc1 = fmaf(bfbits2f((u16)(u >> 16)), d2, acc1);
    }
    int c = lane * 2;
    float b0, b1;
    if (flag) {
        b0 = ((const float*)bias)[c];
        b1 = ((const float*)bias)[c + 1];
    } else {
        b0 = bfbits2f(((const u16*)bias)[c]);
        b1 = bfbits2f(((const u16*)bias)[c + 1]);
    }
    acc0 += b0;
    acc1 += b1;
    if (RELU) {
        acc0 = acc0 > 0.f ? acc0 : 0.01f * acc0;
        acc1 = acc1 > 0.f ? acc1 : 0.01f * acc1;
    }
    if (OUT_BF16) {
        u32 packed = (u32)f2bf(acc0) | ((u32)f2bf(acc1) << 16);
        *(u32*)((u16*)out + (size_t)d * DIM + c) = packed;
    } else {
        *(float2*)((float*)out + (size_t)d * DIM + c) = make_float2(acc0, acc1);
    }
}

extern "C" void kernel_launch(void* const* d_in, const int* in_sizes, int n_in,
                              void* d_out, int out_size, void* d_ws, size_t ws_size,
                              hipStream_t stream) {
    const void* x  = d_in[0];             // f32 (probed; flag-adaptive)
    const int*  ei = (const int*)d_in[1];
    // d_in[2] = batch (unused in eval mode)
    const void* W1 = d_in[3];
    const void* b1 = d_in[4];
    const void* W2 = d_in[5];
    const void* b2 = d_in[6];

    const int N = in_sizes[0] / DIM;
    const int E = in_sizes[1] / 2;
    const int* src = ei;
    const int* dst = ei + E;
    const int chunk = (N + NCHUNK - 1) / NCHUNK;

    // ws layout (~17 MB total; 256B-aligned slices)
    char* ws = (char*)d_ws;
    size_t o = 0;
    int*   flagp    = (int*)(ws + o);   o += 256;
    float* dis      = (float*)(ws + o); o += (((size_t)N * 4 + 255) & ~(size_t)255);
    int*   counts   = (int*)(ws + o);   o += (((size_t)N * 4 + 255) & ~(size_t)255);
    int*   rowptr   = (int*)(ws + o);   o += (((size_t)(N + 1) * 4 + 255) & ~(size_t)255);
    int*   chunksum = (int*)(ws + o);   o += 1024;
    int*   chunkbase= (int*)(ws + o);   o += 1024;
    u32*   elist    = (u32*)(ws + o);   o += (((size_t)E * 4 + 255) & ~(size_t)255);
    u16*   h        = (u16*)(ws + o);   // N*128 bf16 = 12.8 MB

    const int eblk = (E + 255) / 256;
    const int gblk = (N + 7) / 8;
    const int ablk = (N + 3) / 4;

    // dtype probe + CSR build (shared by both layers)
    k_probe<<<1, 64, 0, stream>>>((const u16*)x, flagp);
    hipMemsetAsync(counts, 0, (size_t)N * 4, stream);
    k_count<<<eblk, 256, 0, stream>>>(dst, counts, E);
    k_chunksum<<<NCHUNK, 256, 0, stream>>>(counts, chunksum, N, chunk);
    k_scanbase<<<1, 64, 0, stream>>>(chunksum, chunkbase, rowptr, N);
    k_rowptr<<<NCHUNK, 256, 0, stream>>>(counts, chunkbase, rowptr, dis, N, chunk);
    hipMemsetAsync(counts, 0, (size_t)N * 4, stream);  // reuse as fill cursor
    k_fill<<<eblk, 256, 0, stream>>>(src, dst, rowptr, counts, dis, elist, E);

    // layer-1 activations (bf16) live in d_out's first 12.8 MB (d_out is 25.6 MB f32);
    // consumed by gemm2 BEFORE the final f32 aggregate overwrites d_out.
    u16* act = (u16*)d_out;

    // ---- layer 1 ----
    k_gemm<<<gblk, 256, 0, stream>>>(x, W1, h, N, flagp, 1);
    k_agg<true, true><<<ablk, 256, 0, stream>>>(h, dis, rowptr, elist, b1, act, N, flagp);

    // ---- layer 2 ----
    k_gemm<<<gblk, 256, 0, stream>>>(act, W2, h, N, flagp, 0);
    k_agg<false, false><<<ablk, 256, 0, stream>>>(h, dis, rowptr, elist, b2, d_out, N, flagp);
}

// Round 8
// 300.453 us; speedup vs baseline: 1.5310x; 1.2750x over previous
//
#include <hip/hip_runtime.h>
#include <hip/hip_bf16.h>
#include <hip/hip_fp16.h>

#define DIM 128
#define NCHUNK 256  // chunks for 2-level scan
#define XLD 136     // padded LDS row stride (bf16 elems): 272B -> 2-way bank aliasing (free)
#define WLD 136

typedef unsigned short u16;
typedef unsigned int u32;
typedef __attribute__((ext_vector_type(8))) short bf16x8;  // 8 bf16 = 4 VGPRs
typedef __attribute__((ext_vector_type(4))) float f32x4;

__device__ __forceinline__ float bfbits2f(u16 u) {
    return __uint_as_float(((u32)u) << 16);
}
__device__ __forceinline__ u16 f2bf(float f) {
    __hip_bfloat16 b = __float2bfloat16(f);
    return *reinterpret_cast<u16*>(&b);
}
__device__ __forceinline__ float h16tof(u16 u) {
    __half hh = *reinterpret_cast<__half*>(&u);
    return __half2float(hh);
}
__device__ __forceinline__ u16 ftoh16(float f) {
    __half hh = __float2half(f);
    return *reinterpret_cast<u16*>(&hh);
}

// ---- dtype probe: flag=1 if float tensors are f32, flag=0 if bf16 ----
__global__ void k_probe(const u16* __restrict__ x, int* __restrict__ flagp) {
    if (threadIdx.x == 0 && blockIdx.x == 0) {
        int weird = 0;
        for (int i = 0; i < 256; i += 2) {
            u16 v = x[i];
            int e = (v >> 7) & 0xff;
            if ((v & 0x7fff) != 0 && (e >= 133 || e <= 100)) weird++;
        }
        *flagp = (weird > 16) ? 1 : 0;
    }
}

// ---- CSR build ----
__global__ __launch_bounds__(256) void k_count(const int* __restrict__ dst,
                                               int* __restrict__ counts, int E) {
    int e = blockIdx.x * blockDim.x + threadIdx.x;
    if (e < E) atomicAdd(&counts[dst[e]], 1);
}

__global__ __launch_bounds__(256) void k_chunksum(const int* __restrict__ counts,
                                                  int* __restrict__ chunksum,
                                                  int N, int chunk) {
    __shared__ int r[256];
    int t = threadIdx.x, b = blockIdx.x;
    int idx = b * chunk + t;
    r[t] = (t < chunk && idx < N) ? counts[idx] : 0;
    __syncthreads();
    for (int off = 128; off > 0; off >>= 1) {
        if (t < off) r[t] += r[t + off];
        __syncthreads();
    }
    if (t == 0) chunksum[b] = r[0];
}

__global__ void k_scanbase(const int* __restrict__ chunksum,
                           int* __restrict__ chunkbase,
                           int* __restrict__ rowptr, int N) {
    if (threadIdx.x == 0 && blockIdx.x == 0) {
        int run = 0;
        for (int i = 0; i < NCHUNK; ++i) { chunkbase[i] = run; run += chunksum[i]; }
        rowptr[N] = run;
    }
}

__global__ __launch_bounds__(256) void k_rowptr(const int* __restrict__ counts,
                                                const int* __restrict__ chunkbase,
                                                int* __restrict__ rowptr,
                                                float* __restrict__ dis,
                                                int N, int chunk) {
    __shared__ int sc[256];
    int t = threadIdx.x, b = blockIdx.x;
    int idx = b * chunk + t;
    int v = (t < chunk && idx < N) ? counts[idx] : 0;
    sc[t] = v;
    __syncthreads();
    for (int off = 1; off < 256; off <<= 1) {
        int add = (t >= off) ? sc[t - off] : 0;
        __syncthreads();
        sc[t] += add;
        __syncthreads();
    }
    if (t < chunk && idx < N) {
        rowptr[idx] = chunkbase[b] + sc[t] - v;  // exclusive prefix
        dis[idx] = rsqrtf((float)v + 1.0f);
    }
}

// ---- counting-sort fill with packed payload: elist[pos] = (src<<16) | f16(dis[src]) ----
__global__ __launch_bounds__(256) void k_fill(const int* __restrict__ src,
                                              const int* __restrict__ dst,
                                              const int* __restrict__ rowptr,
                                              int* __restrict__ cursor,
                                              const float* __restrict__ dis,
                                              u32* __restrict__ elist, int E) {
    int e = blockIdx.x * blockDim.x + threadIdx.x;
    if (e < E) {
        int d = dst[e];
        int s = src[e];
        int pos = rowptr[d] + atomicAdd(&cursor[d], 1);
        elist[pos] = ((u32)s << 16) | (u32)ftoh16(dis[s]);
    }
}

// ---- MFMA GEMM: h[n,o] = sum_k in[n,k]*W[o,k]; h stored bf16.
// Block = 256 thr = 4 waves; tile = 64 nodes x 128 out-cols, K=128.
// LDS: X 64x136 bf16 + W 128x136 bf16 = 52.2 KB. Wave w owns rows w*16..w*16+15;
// 8 col-tiles x 4 K-slabs of v_mfma_f32_16x16x32_bf16.
// in_mode: 1 = input follows flag (layer 1); 0 = input always bf16 (layer-2 act).
__global__ __launch_bounds__(256) void k_gemm(const void* __restrict__ in,
                                              const void* __restrict__ W,
                                              u16* __restrict__ h, int N,
                                              const int* __restrict__ flagp, int in_mode) {
    __shared__ u16 Xs[64 * XLD];
    __shared__ u16 Wsh[128 * WLD];
    const int tid = threadIdx.x;
    const int flag = *flagp;
    const int in_f32 = in_mode ? flag : 0;
    const int n0 = blockIdx.x * 64;

    // ---- stage W (128x128 -> bf16, padded rows) ----
    if (flag) {
        const float* Wf = (const float*)W;
        for (int t = tid; t < 128 * 32; t += 256) {      // t indexes float4
            int r = t >> 5, c4 = (t & 31) * 4;
            float4 w = *(const float4*)(Wf + r * DIM + c4);
            u16* p = Wsh + r * WLD + c4;
            p[0] = f2bf(w.x); p[1] = f2bf(w.y); p[2] = f2bf(w.z); p[3] = f2bf(w.w);
        }
    } else {
        const u16* Wu = (const u16*)W;
        for (int t = tid; t < 128 * 16; t += 256) {      // t indexes 16B chunks
            int r = t >> 4, c8 = (t & 15) * 8;
            *(int4*)(Wsh + r * WLD + c8) = *(const int4*)(Wu + r * DIM + c8);
        }
    }
    // ---- stage X tile (64 rows -> bf16, padded rows; zero-fill past N) ----
    if (in_f32) {
        const float* xf = (const float*)in;
        for (int t = tid; t < 64 * 32; t += 256) {       // t indexes float4
            int r = t >> 5, c4 = (t & 31) * 4;
            int n = n0 + r;
            float4 xv = make_float4(0.f, 0.f, 0.f, 0.f);
            if (n < N) xv = *(const float4*)(xf + (size_t)n * DIM + c4);
            u16* p = Xs + r * XLD + c4;
            p[0] = f2bf(xv.x); p[1] = f2bf(xv.y); p[2] = f2bf(xv.z); p[3] = f2bf(xv.w);
        }
    } else {
        const u16* xu = (const u16*)in;
        for (int t = tid; t < 64 * 16; t += 256) {       // t indexes 16B chunks
            int r = t >> 4, c8 = (t & 15) * 8;
            int n = n0 + r;
            int4 v = make_int4(0, 0, 0, 0);
            if (n < N) v = *(const int4*)(xu + (size_t)n * DIM + c8);
            *(int4*)(Xs + r * XLD + c8) = v;
        }
    }
    __syncthreads();

    const int wid = tid >> 6;
    const int lane = tid & 63;
    const int m_base = wid * 16;
    const int idx16 = lane & 15;        // A: row / B: col / D: col
    const int koff = (lane >> 4) * 8;   // K packing within 32-slab

    // preload A fragments for all 4 K-slabs (one ds_read_b128 each)
    bf16x8 afrag[4];
#pragma unroll
    for (int ks = 0; ks < 4; ++ks)
        afrag[ks] = *(const bf16x8*)(Xs + (m_base + idx16) * XLD + ks * 32 + koff);

    f32x4 acc[8];
#pragma unroll
    for (int ct = 0; ct < 8; ++ct) acc[ct] = (f32x4){0.f, 0.f, 0.f, 0.f};

#pragma unroll
    for (int ct = 0; ct < 8; ++ct) {
#pragma unroll
        for (int ks = 0; ks < 4; ++ks) {
            bf16x8 bfrag = *(const bf16x8*)(Wsh + (ct * 16 + idx16) * WLD + ks * 32 + koff);
            acc[ct] = __builtin_amdgcn_mfma_f32_16x16x32_bf16(afrag[ks], bfrag, acc[ct], 0, 0, 0);
        }
    }

    // D layout (m89-verified): col = lane&15, row = (lane>>4)*4 + reg
    const int drow = (lane >> 4) * 4;
#pragma unroll
    for (int ct = 0; ct < 8; ++ct) {
#pragma unroll
        for (int r = 0; r < 4; ++r) {
            int row = n0 + m_base + drow + r;
            if (row < N) h[(size_t)row * DIM + ct * 16 + idx16] = f2bf(acc[ct][r]);
        }
    }
}

// ---- fused CSR aggregate: one wave per dst node d, 2 cols per lane.
// Unrolled x4 with independent accumulators; packed (src|f16 dis) edge payload.
// OUT_BF16=true -> bf16 store (layer-1 act); false -> f32 store (final output).
template <bool RELU, bool OUT_BF16>
__global__ __launch_bounds__(256) void k_agg(const u16* __restrict__ h,
                                             const float* __restrict__ dis,
                                             const int* __restrict__ rowptr,
                                             const u32* __restrict__ elist,
                                             const void* __restrict__ bias,
                                             void* __restrict__ out, int N,
                                             const int* __restrict__ flagp) {
    const int lane = threadIdx.x & 63;
    const int d = blockIdx.x * 4 + (threadIdx.x >> 6);
    if (d >= N) return;
    const int flag = *flagp;

    const int start = rowptr[d];
    const int end = rowptr[d + 1];
    const float dd = dis[d];

    float p0 = 0.f, p1 = 0.f, q0 = 0.f, q1 = 0.f;
    float r0 = 0.f, r1 = 0.f, t0 = 0.f, t1 = 0.f;

    int j = start;
    for (; j + 4 <= end; j += 4) {
        u32 e0 = elist[j];
        u32 e1 = elist[j + 1];
        u32 e2 = elist[j + 2];
        u32 e3 = elist[j + 3];
        float w0 = h16tof((u16)(e0 & 0xffff));
        float w1 = h16tof((u16)(e1 & 0xffff));
        float w2 = h16tof((u16)(e2 & 0xffff));
        float w3 = h16tof((u16)(e3 & 0xffff));
        u32 u0 = *(const u32*)(h + ((size_t)(e0 >> 16)) * DIM + lane * 2);
        u32 u1 = *(const u32*)(h + ((size_t)(e1 >> 16)) * DIM + lane * 2);
        u32 u2 = *(const u32*)(h + ((size_t)(e2 >> 16)) * DIM + lane * 2);
        u32 u3 = *(const u32*)(h + ((size_t)(e3 >> 16)) * DIM + lane * 2);
        p0 = fmaf(bfbits2f((u16)(u0 & 0xffff)), w0, p0);
        p1 = fmaf(bfbits2f((u16)(u0 >> 16)), w0, p1);
        q0 = fmaf(bfbits2f((u16)(u1 & 0xffff)), w1, q0);
        q1 = fmaf(bfbits2f((u16)(u1 >> 16)), w1, q1);
        r0 = fmaf(bfbits2f((u16)(u2 & 0xffff)), w2, r0);
        r1 = fmaf(bfbits2f((u16)(u2 >> 16)), w2, r1);
        t0 = fmaf(bfbits2f((u16)(u3 & 0xffff)), w3, t0);
        t1 = fmaf(bfbits2f((u16)(u3 >> 16)), w3, t1);
    }
    for (; j < end; ++j) {
        u32 e0 = elist[j];
        float w0 = h16tof((u16)(e0 & 0xffff));
        u32 u0 = *(const u32*)(h + ((size_t)(e0 >> 16)) * DIM + lane * 2);
        p0 = fmaf(bfbits2f((u16)(u0 & 0xffff)), w0, p0);
        p1 = fmaf(bfbits2f((u16)(u0 >> 16)), w0, p1);
    }
    float acc0 = (p0 + q0) + (r0 + t0);
    float acc1 = (p1 + q1) + (r1 + t1);
    acc0 *= dd;
    acc1 *= dd;
    {   // self-loop
        float d2 = dd * dd;
        u32 u = *(const u32*)(h + (size_t)d * DIM + lane * 2);
        acc0 = fmaf(bfbits2f((u16)(u & 0xffff)), d2, acc0);
        acc1 = fmaf(bfbits2f((u16)(u >> 16)), d2, acc1);
    }
    int c = lane * 2;
    float b0, b1;
    if (flag) {
        b0 = ((const float*)bias)[c];
        b1 = ((const float*)bias)[c + 1];
    } else {
        b0 = bfbits2f(((const u16*)bias)[c]);
        b1 = bfbits2f(((const u16*)bias)[c + 1]);
    }
    acc0 += b0;
    acc1 += b1;
    if (RELU) {
        acc0 = acc0 > 0.f ? acc0 : 0.01f * acc0;
        acc1 = acc1 > 0.f ? acc1 : 0.01f * acc1;
    }
    if (OUT_BF16) {
        u32 packed = (u32)f2bf(acc0) | ((u32)f2bf(acc1) << 16);
        *(u32*)((u16*)out + (size_t)d * DIM + c) = packed;
    } else {
        *(float2*)((float*)out + (size_t)d * DIM + c) = make_float2(acc0, acc1);
    }
}

extern "C" void kernel_launch(void* const* d_in, const int* in_sizes, int n_in,
                              void* d_out, int out_size, void* d_ws, size_t ws_size,
                              hipStream_t stream) {
    const void* x  = d_in[0];             // f32 (probed; flag-adaptive)
    const int*  ei = (const int*)d_in[1];
    // d_in[2] = batch (unused in eval mode)
    const void* W1 = d_in[3];
    const void* b1 = d_in[4];
    const void* W2 = d_in[5];
    const void* b2 = d_in[6];

    const int N = in_sizes[0] / DIM;
    const int E = in_sizes[1] / 2;
    const int* src = ei;
    const int* dst = ei + E;
    const int chunk = (N + NCHUNK - 1) / NCHUNK;

    // ws layout (~17 MB total; 256B-aligned slices)
    char* ws = (char*)d_ws;
    size_t o = 0;
    int*   flagp    = (int*)(ws + o);   o += 256;
    float* dis      = (float*)(ws + o); o += (((size_t)N * 4 + 255) & ~(size_t)255);
    int*   counts   = (int*)(ws + o);   o += (((size_t)N * 4 + 255) & ~(size_t)255);
    int*   rowptr   = (int*)(ws + o);   o += (((size_t)(N + 1) * 4 + 255) & ~(size_t)255);
    int*   chunksum = (int*)(ws + o);   o += 1024;
    int*   chunkbase= (int*)(ws + o);   o += 1024;
    u32*   elist    = (u32*)(ws + o);   o += (((size_t)E * 4 + 255) & ~(size_t)255);
    u16*   h        = (u16*)(ws + o);   // N*128 bf16 = 12.8 MB

    const int eblk = (E + 255) / 256;
    const int gblk = (N + 63) / 64;
    const int ablk = (N + 3) / 4;

    // dtype probe + CSR build (shared by both layers)
    k_probe<<<1, 64, 0, stream>>>((const u16*)x, flagp);
    hipMemsetAsync(counts, 0, (size_t)N * 4, stream);
    k_count<<<eblk, 256, 0, stream>>>(dst, counts, E);
    k_chunksum<<<NCHUNK, 256, 0, stream>>>(counts, chunksum, N, chunk);
    k_scanbase<<<1, 64, 0, stream>>>(chunksum, chunkbase, rowptr, N);
    k_rowptr<<<NCHUNK, 256, 0, stream>>>(counts, chunkbase, rowptr, dis, N, chunk);
    hipMemsetAsync(counts, 0, (size_t)N * 4, stream);  // reuse as fill cursor
    k_fill<<<eblk, 256, 0, stream>>>(src, dst, rowptr, counts, dis, elist, E);

    // layer-1 activations (bf16) live in d_out's first 12.8 MB (d_out is 25.6 MB f32);
    // consumed by gemm2 BEFORE the final f32 aggregate overwrites d_out.
    u16* act = (u16*)d_out;

    // ---- layer 1 ----
    k_gemm<<<gblk, 256, 0, stream>>>(x, W1, h, N, flagp, 1);
    k_agg<true, true><<<ablk, 256, 0, stream>>>(h, dis, rowptr, elist, b1, act, N, flagp);

    // ---- layer 2 ----
    k_gemm<<<gblk, 256, 0, stream>>>(act, W2, h, N, flagp, 0);
    k_agg<false, false><<<ablk, 256, 0, stream>>>(h, dis, rowptr, elist, b2, d_out, N, flagp);
}